// Round 1
// baseline (421.480 us; speedup 1.0000x reference)
//
#include <hip/hip_runtime.h>

// SSM: h_t = A h_{t-1} + B x_t ; y_t = C h_t + D x_t
// BATCH=128, T=2048, N=D_IN=D_OUT=64, all float32.
// Chunked parallel scan: 32 chunks of 64 steps.
//   K0 (x6): A^64 via repeated squaring (ping-pong)
//   K1: per-(b,chunk) local scan from 0 -> chunk-final local state f
//   K2: per-batch sequential scan over 32 chunks: S_c = A^64 S_{c-1} + f_c
//       (stores S_{c-1}, the entry state of each chunk)
//   K3: per-(b,chunk) scan from S_{c-1}, writes true h into d_out
//   K4: y = C h + D x, in-place over d_out
// Matvecs: per-lane matrix rows in VGPRs, v_readlane broadcast of the vector.

#define T_SEQ 2048
#define NBATCH 128
#define CHUNK 64
#define NCHUNK 32

__device__ __forceinline__ float bcast(float v, int l) {
    return __int_as_float(__builtin_amdgcn_readlane(__float_as_int(v), l));
}

__device__ __forceinline__ void load_row(const float* __restrict__ M, int lane, float* r) {
    const float4* M4 = (const float4*)(M + lane * 64);
#pragma unroll
    for (int q = 0; q < 16; ++q) {
        float4 v = M4[q];
        r[q * 4 + 0] = v.x; r[q * 4 + 1] = v.y;
        r[q * 4 + 2] = v.z; r[q * 4 + 3] = v.w;
    }
}

// ---- K0: dst = src @ src (64x64), 64 blocks x 64 threads ----
__global__ void k_square(const float* __restrict__ src, float* __restrict__ dst) {
    int r = blockIdx.x;
    int c = threadIdx.x;
    float acc = 0.f;
#pragma unroll 8
    for (int k = 0; k < 64; ++k)
        acc = fmaf(src[r * 64 + k], src[k * 64 + c], acc);
    dst[r * 64 + c] = acc;
}

// ---- K1: local chunk scan from zero; emit final local state ----
__global__ __launch_bounds__(256) void k_pass1(const float* __restrict__ x,
                                               const float* __restrict__ A,
                                               const float* __restrict__ B,
                                               float* __restrict__ f) {
    int wave = blockIdx.x * 4 + (threadIdx.x >> 6);  // 0..4095
    int lane = threadIdx.x & 63;
    int b = wave >> 5;      // 0..127
    int c = wave & 31;      // 0..31

    float Ar[64], Br[64];
    load_row(A, lane, Ar);
    load_row(B, lane, Br);

    float h = 0.f;
    const float* xp = x + ((long)b * T_SEQ + (long)c * CHUNK) * 64 + lane;

    for (int j = 0; j < CHUNK; ++j) {
        float xv = xp[(long)j * 64];
        float a0 = 0.f, a1 = 0.f;
#pragma unroll
        for (int m = 0; m < 64; m += 2) {
            a0 = fmaf(Br[m],     bcast(xv, m),     a0);
            a1 = fmaf(Br[m + 1], bcast(xv, m + 1), a1);
        }
#pragma unroll
        for (int m = 0; m < 64; m += 2) {
            a0 = fmaf(Ar[m],     bcast(h, m),     a0);
            a1 = fmaf(Ar[m + 1], bcast(h, m + 1), a1);
        }
        h = a0 + a1;
    }
    f[((long)b * NCHUNK + c) * 64 + lane] = h;
}

// ---- K2: boundary scan over chunks: S_c = M S_{c-1} + f_c ----
__global__ __launch_bounds__(256) void k_boundary(const float* __restrict__ M,
                                                  const float* __restrict__ f,
                                                  float* __restrict__ Sprev) {
    int b = blockIdx.x * 4 + (threadIdx.x >> 6);  // 0..127
    int lane = threadIdx.x & 63;

    float Mr[64];
    load_row(M, lane, Mr);

    float S = 0.f;
    for (int c = 0; c < NCHUNK; ++c) {
        long idx = ((long)b * NCHUNK + c) * 64 + lane;
        Sprev[idx] = S;  // state entering chunk c
        float a0 = f[idx], a1 = 0.f;
#pragma unroll
        for (int m = 0; m < 64; m += 2) {
            a0 = fmaf(Mr[m],     bcast(S, m),     a0);
            a1 = fmaf(Mr[m + 1], bcast(S, m + 1), a1);
        }
        S = a0 + a1;
    }
}

// ---- K3: true scan from S_{c-1}; write h into out ----
__global__ __launch_bounds__(256) void k_pass3(const float* __restrict__ x,
                                               const float* __restrict__ A,
                                               const float* __restrict__ B,
                                               const float* __restrict__ Sprev,
                                               float* __restrict__ out) {
    int wave = blockIdx.x * 4 + (threadIdx.x >> 6);
    int lane = threadIdx.x & 63;
    int b = wave >> 5;
    int c = wave & 31;

    float Ar[64], Br[64];
    load_row(A, lane, Ar);
    load_row(B, lane, Br);

    float h = Sprev[((long)b * NCHUNK + c) * 64 + lane];
    const float* xp = x + ((long)b * T_SEQ + (long)c * CHUNK) * 64 + lane;
    float* op = out + ((long)b * T_SEQ + (long)c * CHUNK) * 64 + lane;

    for (int j = 0; j < CHUNK; ++j) {
        float xv = xp[(long)j * 64];
        float a0 = 0.f, a1 = 0.f;
#pragma unroll
        for (int m = 0; m < 64; m += 2) {
            a0 = fmaf(Br[m],     bcast(xv, m),     a0);
            a1 = fmaf(Br[m + 1], bcast(xv, m + 1), a1);
        }
#pragma unroll
        for (int m = 0; m < 64; m += 2) {
            a0 = fmaf(Ar[m],     bcast(h, m),     a0);
            a1 = fmaf(Ar[m + 1], bcast(h, m + 1), a1);
        }
        h = a0 + a1;
        op[(long)j * 64] = h;
    }
}

// ---- K4: y = C h + D x, in-place (h staged in out) ----
__global__ __launch_bounds__(256) void k_output(const float* __restrict__ x,
                                                const float* __restrict__ C,
                                                const float* __restrict__ D,
                                                float* __restrict__ out) {
    int wave = blockIdx.x * 4 + (threadIdx.x >> 6);  // 0..4095
    int lane = threadIdx.x & 63;

    float Cr[64], Dr[64];
    load_row(C, lane, Cr);
    load_row(D, lane, Dr);

    const long ntask = (long)NBATCH * T_SEQ;
    for (long task = wave; task < ntask; task += 4096) {
        float hv = out[task * 64 + lane];
        float xv = x[task * 64 + lane];
        float a0 = 0.f, a1 = 0.f, a2 = 0.f, a3 = 0.f;
#pragma unroll
        for (int m = 0; m < 64; m += 2) {
            a0 = fmaf(Cr[m],     bcast(hv, m),     a0);
            a1 = fmaf(Cr[m + 1], bcast(hv, m + 1), a1);
            a2 = fmaf(Dr[m],     bcast(xv, m),     a2);
            a3 = fmaf(Dr[m + 1], bcast(xv, m + 1), a3);
        }
        out[task * 64 + lane] = (a0 + a1) + (a2 + a3);
    }
}

extern "C" void kernel_launch(void* const* d_in, const int* in_sizes, int n_in,
                              void* d_out, int out_size, void* d_ws, size_t ws_size,
                              hipStream_t stream) {
    const float* x  = (const float*)d_in[0];
    const float* A  = (const float*)d_in[1];
    const float* B  = (const float*)d_in[2];
    const float* C  = (const float*)d_in[3];
    const float* D  = (const float*)d_in[4];
    float* out = (float*)d_out;

    float* ws    = (float*)d_ws;
    float* f     = ws;                         // 128*32*64 = 262144 floats (1 MB)
    float* Sprev = ws + 262144;                // 262144 floats (1 MB)
    float* P0    = ws + 524288;                // 4096 floats
    float* P1    = P0 + 4096;                  // 4096 floats

    // A^64 by repeated squaring: A->A^2->A^4->A^8->A^16->A^32->A^64
    k_square<<<64, 64, 0, stream>>>(A,  P0);
    k_square<<<64, 64, 0, stream>>>(P0, P1);
    k_square<<<64, 64, 0, stream>>>(P1, P0);
    k_square<<<64, 64, 0, stream>>>(P0, P1);
    k_square<<<64, 64, 0, stream>>>(P1, P0);
    k_square<<<64, 64, 0, stream>>>(P0, P1);   // P1 = A^64

    k_pass1<<<1024, 256, 0, stream>>>(x, A, B, f);
    k_boundary<<<32, 256, 0, stream>>>(P1, f, Sprev);
    k_pass3<<<1024, 256, 0, stream>>>(x, A, B, Sprev, out);
    k_output<<<1024, 256, 0, stream>>>(x, C, D, out);
}

// Round 4
// 131.463 us; speedup vs baseline: 3.2061x; 3.2061x over previous
//
#include <hip/hip_runtime.h>

// SSM: h_t = A h_{t-1} + B x_t ; y_t = C h_t + D x_t
// BATCH=128, T=2048, N=64. All matmuls via mfma_f32_16x16x32_bf16 with
// split-bf16 (hi+lo, 3-mult) for ~f32 accuracy.
//
// Structure:
//   k_prep:     blocks 0..31: P_{j+1}=A^{j+1} (split-MFMA binary exp, A symmetric),
//               E_j = C*A^{j+1} (split), block31 stores P32 f32; block 32: A/B/C/D splits.
//   k_pass1:    per (chunk c of 32 steps, batch-group g of 16): local scan from 0,
//               H_j = H_{j-1} A^T + x_j B^T ; writes y_partial = C H_j + D x_j to out;
//               writes chunk-final state f.  LDS double-buffered H (stride-72 pad).
//   k_boundary: f32 readlane scan over 64 chunks with P32; emits S (entry states) hi/lo.
//   k_corr:     y += E_j * S[b,c]   (pure streaming MFMA, no LDS).

#define T_SEQ 2048
#define NBATCH 128
#define LCH 32      // chunk length
#define NCH 64      // number of chunks

typedef __bf16 bf16x8 __attribute__((ext_vector_type(8)));
typedef float f32x4 __attribute__((ext_vector_type(4)));
#define MFMA16(a, b, c) __builtin_amdgcn_mfma_f32_16x16x32_bf16(a, b, c, 0, 0, 0)

__device__ __forceinline__ float bcast(float v, int l) {
    return __int_as_float(__builtin_amdgcn_readlane(__float_as_int(v), l));
}

__device__ __forceinline__ void split_f32x8(f32x4 a, f32x4 b, bf16x8& hi, bf16x8& lo) {
#pragma unroll
    for (int i = 0; i < 4; ++i) {
        float v = a[i]; __bf16 h = (__bf16)v; hi[i] = h; lo[i] = (__bf16)(v - (float)h);
        v = b[i]; h = (__bf16)v; hi[4 + i] = h; lo[4 + i] = (__bf16)(v - (float)h);
    }
}

// ---------------- k_prep ----------------
// In-LDS split matmul step: D = X @ Y, Y must be symmetric (B-operand row-read).
// 4 waves, wave w owns output cols w*16..w*16+15.
__device__ __forceinline__ void mmstep(int w, int fr, int fq,
        const __bf16 (*Xh)[72], const __bf16 (*Xl)[72],
        const __bf16 (*Yh)[72], const __bf16 (*Yl)[72],
        __bf16 (*Dh)[72], __bf16 (*Dl)[72]) {
    f32x4 accs[4];
#pragma unroll
    for (int mt = 0; mt < 4; ++mt) {
        f32x4 acc = {0.f, 0.f, 0.f, 0.f};
#pragma unroll
        for (int kk = 0; kk < 2; ++kk) {
            bf16x8 xh = *(const bf16x8*)&Xh[mt * 16 + fr][fq * 8 + kk * 32];
            bf16x8 xl = *(const bf16x8*)&Xl[mt * 16 + fr][fq * 8 + kk * 32];
            bf16x8 yh = *(const bf16x8*)&Yh[w * 16 + fr][fq * 8 + kk * 32];
            bf16x8 yl = *(const bf16x8*)&Yl[w * 16 + fr][fq * 8 + kk * 32];
            acc = MFMA16(xh, yh, acc);
            acc = MFMA16(xh, yl, acc);
            acc = MFMA16(xl, yh, acc);
        }
        accs[mt] = acc;
    }
    __syncthreads();
#pragma unroll
    for (int mt = 0; mt < 4; ++mt)
#pragma unroll
        for (int r = 0; r < 4; ++r) {
            float v = accs[mt][r]; __bf16 h = (__bf16)v;
            Dh[mt * 16 + fq * 4 + r][w * 16 + fr] = h;
            Dl[mt * 16 + fq * 4 + r][w * 16 + fr] = (__bf16)(v - (float)h);
        }
    __syncthreads();
}

__global__ __launch_bounds__(256) void k_prep(const float* __restrict__ A,
        const float* __restrict__ B, const float* __restrict__ C,
        const float* __restrict__ D, float* __restrict__ P32,
        __bf16* __restrict__ E_hi, __bf16* __restrict__ E_lo,
        __bf16* __restrict__ A_hi, __bf16* __restrict__ A_lo,
        __bf16* __restrict__ B_hi, __bf16* __restrict__ B_lo,
        __bf16* __restrict__ C_hi, __bf16* __restrict__ C_lo,
        __bf16* __restrict__ D_bf) {
    int bid = blockIdx.x;
    if (bid == 32) {
        for (int i = threadIdx.x; i < 4096; i += 256) {
            float a = A[i]; __bf16 h = (__bf16)a; A_hi[i] = h; A_lo[i] = (__bf16)(a - (float)h);
            float b = B[i]; h = (__bf16)b; B_hi[i] = h; B_lo[i] = (__bf16)(b - (float)h);
            float c = C[i]; h = (__bf16)c; C_hi[i] = h; C_lo[i] = (__bf16)(c - (float)h);
            D_bf[i] = (__bf16)D[i];
        }
        return;
    }
    __shared__ __align__(16) __bf16 Ah[64][72], Al[64][72];
    __shared__ __align__(16) __bf16 X1h[64][72], X1l[64][72];
    __shared__ __align__(16) __bf16 X2h[64][72], X2l[64][72];
    for (int i = threadIdx.x; i < 4096; i += 256) {
        int r = i >> 6, cc = i & 63;
        float a = A[i]; __bf16 h = (__bf16)a, l = (__bf16)(a - (float)h);
        Ah[r][cc] = h; Al[r][cc] = l; X1h[r][cc] = h; X1l[r][cc] = l;
    }
    __syncthreads();
    int e = bid + 1;
    int w = threadIdx.x >> 6, lane = threadIdx.x & 63;
    int fr = lane & 15, fq = lane >> 4;
    __bf16 (*curh)[72] = X1h, (*curl)[72] = X1l;
    __bf16 (*oth)[72] = X2h, (*otl)[72] = X2l;
    int msb = 31 - __builtin_clz((unsigned)e);
    for (int bit = msb - 1; bit >= 0; --bit) {
        mmstep(w, fr, fq, curh, curl, curh, curl, oth, otl);   // square
        { __bf16 (*t1)[72] = curh; curh = oth; oth = t1;
          __bf16 (*t2)[72] = curl; curl = otl; otl = t2; }
        if ((e >> bit) & 1) {
            mmstep(w, fr, fq, curh, curl, Ah, Al, oth, otl);   // * A
            { __bf16 (*t1)[72] = curh; curh = oth; oth = t1;
              __bf16 (*t2)[72] = curl; curl = otl; otl = t2; }
        }
    }
    if (bid == 31) {  // P32 f32
        for (int i = threadIdx.x; i < 4096; i += 256) {
            int r = i >> 6, cc = i & 63;
            P32[i] = (float)curh[r][cc] + (float)curl[r][cc];
        }
    }
    // overwrite Ah/Al with C-split, then E = C @ cur
    __syncthreads();
    for (int i = threadIdx.x; i < 4096; i += 256) {
        int r = i >> 6, cc = i & 63;
        float v = C[i]; __bf16 h = (__bf16)v;
        Ah[r][cc] = h; Al[r][cc] = (__bf16)(v - (float)h);
    }
    __syncthreads();
#pragma unroll
    for (int mt = 0; mt < 4; ++mt) {
        f32x4 acc = {0.f, 0.f, 0.f, 0.f};
#pragma unroll
        for (int kk = 0; kk < 2; ++kk) {
            bf16x8 xh = *(const bf16x8*)&Ah[mt * 16 + fr][fq * 8 + kk * 32];
            bf16x8 xl = *(const bf16x8*)&Al[mt * 16 + fr][fq * 8 + kk * 32];
            bf16x8 yh = *(const bf16x8*)&curh[w * 16 + fr][fq * 8 + kk * 32];
            bf16x8 yl = *(const bf16x8*)&curl[w * 16 + fr][fq * 8 + kk * 32];
            acc = MFMA16(xh, yh, acc);
            acc = MFMA16(xh, yl, acc);
            acc = MFMA16(xl, yh, acc);
        }
#pragma unroll
        for (int r = 0; r < 4; ++r) {
            float v = acc[r]; __bf16 h = (__bf16)v;
            int off = bid * 4096 + (mt * 16 + fq * 4 + r) * 64 + w * 16 + fr;
            E_hi[off] = h; E_lo[off] = (__bf16)(v - (float)h);
        }
    }
}

// ---------------- k_pass1 ----------------
__global__ __launch_bounds__(256) void k_pass1(const float* __restrict__ x,
        const __bf16* __restrict__ A_hi, const __bf16* __restrict__ A_lo,
        const __bf16* __restrict__ B_hi, const __bf16* __restrict__ B_lo,
        const __bf16* __restrict__ C_hi, const __bf16* __restrict__ C_lo,
        const __bf16* __restrict__ D_bf,
        float* __restrict__ fstate, float* __restrict__ y) {
    int c = blockIdx.x >> 3, g = blockIdx.x & 7;
    int w = threadIdx.x >> 6, lane = threadIdx.x & 63;
    int fr = lane & 15, fq = lane >> 4;

    __shared__ __align__(16) __bf16 Hh[2][16][72], Hl[2][16][72];
    for (int i = threadIdx.x; i < 16 * 72; i += 256) {
        Hh[0][i / 72][i % 72] = (__bf16)0.f; Hl[0][i / 72][i % 72] = (__bf16)0.f;
    }

    // invariant B-operand fragments: elem k -> matrix[row=(n or o)][col=k]
    bf16x8 Afh[2], Afl[2], Bfh[2], Bfl[2], Cfh[2], Cfl[2], Df[2];
#pragma unroll
    for (int kk = 0; kk < 2; ++kk) {
        int off = (w * 16 + fr) * 64 + fq * 8 + kk * 32;
        Afh[kk] = *(const bf16x8*)(A_hi + off); Afl[kk] = *(const bf16x8*)(A_lo + off);
        Bfh[kk] = *(const bf16x8*)(B_hi + off); Bfl[kk] = *(const bf16x8*)(B_lo + off);
        Cfh[kk] = *(const bf16x8*)(C_hi + off); Cfl[kk] = *(const bf16x8*)(C_lo + off);
        Df[kk]  = *(const bf16x8*)(D_bf + off);
    }
    const float* xp = x + ((long)(g * 16 + fr) * T_SEQ + c * LCH) * 64 + fq * 8;
    float* yp = y + ((long)(g * 16 + fq * 4) * T_SEQ + c * LCH) * 64 + w * 16 + fr;
    float* fp = fstate + c * 8192 + (g * 16 + fq * 4) * 64 + w * 16 + fr;
    __syncthreads();

    f32x4 nx0, nx1, nx2, nx3;        // x_j raw f32 (prefetched)
    nx0 = *(const f32x4*)(xp);       nx1 = *(const f32x4*)(xp + 4);
    nx2 = *(const f32x4*)(xp + 32);  nx3 = *(const f32x4*)(xp + 36);
    bf16x8 xsh[2], xsl[2];
    int p = 0;
    for (int j = 0; j < LCH; ++j) {
        // H_{j-1} fragments
        bf16x8 hfh[2], hfl[2];
#pragma unroll
        for (int kk = 0; kk < 2; ++kk) {
            hfh[kk] = *(const bf16x8*)&Hh[p][fr][fq * 8 + kk * 32];
            hfl[kk] = *(const bf16x8*)&Hl[p][fr][fq * 8 + kk * 32];
        }
        // y_{j-1} = C H_{j-1} + D x_{j-1}
        if (j > 0) {
            f32x4 ya = {0.f, 0.f, 0.f, 0.f};
#pragma unroll
            for (int kk = 0; kk < 2; ++kk) {
                ya = MFMA16(hfh[kk], Cfh[kk], ya);
                ya = MFMA16(hfh[kk], Cfl[kk], ya);
                ya = MFMA16(hfl[kk], Cfh[kk], ya);
                ya = MFMA16(xsh[kk], Df[kk], ya);
            }
#pragma unroll
            for (int r = 0; r < 4; ++r)
                yp[(long)r * T_SEQ * 64 + (j - 1) * 64] = ya[r];
        }
        // split x_j
        split_f32x8(nx0, nx1, xsh[0], xsl[0]);
        split_f32x8(nx2, nx3, xsh[1], xsl[1]);
        // prefetch x_{j+1}
        if (j < LCH - 1) {
            const float* q = xp + (j + 1) * 64;
            nx0 = *(const f32x4*)(q);      nx1 = *(const f32x4*)(q + 4);
            nx2 = *(const f32x4*)(q + 32); nx3 = *(const f32x4*)(q + 36);
        }
        // scan step: acc = H A^T + x B^T
        f32x4 acc = {0.f, 0.f, 0.f, 0.f};
#pragma unroll
        for (int kk = 0; kk < 2; ++kk) {
            acc = MFMA16(hfh[kk], Afh[kk], acc);
            acc = MFMA16(hfh[kk], Afl[kk], acc);
            acc = MFMA16(hfl[kk], Afh[kk], acc);
            acc = MFMA16(xsh[kk], Bfh[kk], acc);
            acc = MFMA16(xsh[kk], Bfl[kk], acc);
            acc = MFMA16(xsl[kk], Bfh[kk], acc);
        }
        if (j == LCH - 1) {
#pragma unroll
            for (int r = 0; r < 4; ++r) fp[r * 64] = acc[r];
        }
        // write H_j (split) to other buffer
#pragma unroll
        for (int r = 0; r < 4; ++r) {
            float v = acc[r]; __bf16 h = (__bf16)v;
            Hh[p ^ 1][fq * 4 + r][w * 16 + fr] = h;
            Hl[p ^ 1][fq * 4 + r][w * 16 + fr] = (__bf16)(v - (float)h);
        }
        __syncthreads();
        p ^= 1;
    }
    // epilogue: y_{31}
    bf16x8 hfh[2], hfl[2];
#pragma unroll
    for (int kk = 0; kk < 2; ++kk) {
        hfh[kk] = *(const bf16x8*)&Hh[p][fr][fq * 8 + kk * 32];
        hfl[kk] = *(const bf16x8*)&Hl[p][fr][fq * 8 + kk * 32];
    }
    f32x4 ya = {0.f, 0.f, 0.f, 0.f};
#pragma unroll
    for (int kk = 0; kk < 2; ++kk) {
        ya = MFMA16(hfh[kk], Cfh[kk], ya);
        ya = MFMA16(hfh[kk], Cfl[kk], ya);
        ya = MFMA16(hfl[kk], Cfh[kk], ya);
        ya = MFMA16(xsh[kk], Df[kk], ya);
    }
#pragma unroll
    for (int r = 0; r < 4; ++r)
        yp[(long)r * T_SEQ * 64 + (LCH - 1) * 64] = ya[r];
}

// ---------------- k_boundary ----------------
__global__ __launch_bounds__(256) void k_boundary(const float* __restrict__ P32,
        const float* __restrict__ fstate,
        __bf16* __restrict__ S_hi, __bf16* __restrict__ S_lo) {
    int b = blockIdx.x * 4 + (threadIdx.x >> 6);
    int lane = threadIdx.x & 63;
    float Pr[64];
    const f32x4* P4 = (const f32x4*)(P32 + lane * 64);
#pragma unroll
    for (int q = 0; q < 16; ++q) {
        f32x4 v = P4[q];
        Pr[q * 4] = v[0]; Pr[q * 4 + 1] = v[1]; Pr[q * 4 + 2] = v[2]; Pr[q * 4 + 3] = v[3];
    }
    float S = 0.f;
    for (int c = 0; c < NCH; ++c) {
        long idx = (long)c * 8192 + b * 64 + lane;
        __bf16 h = (__bf16)S;
        S_hi[idx] = h; S_lo[idx] = (__bf16)(S - (float)h);
        float fv = fstate[idx];
        float a0 = fv, a1 = 0.f;
#pragma unroll
        for (int m = 0; m < 64; m += 2) {
            a0 = fmaf(Pr[m], bcast(S, m), a0);
            a1 = fmaf(Pr[m + 1], bcast(S, m + 1), a1);
        }
        S = a0 + a1;
    }
}

// ---------------- k_corr ----------------
__global__ __launch_bounds__(256) void k_corr(float* __restrict__ y,
        const __bf16* __restrict__ S_hi, const __bf16* __restrict__ S_lo,
        const __bf16* __restrict__ E_hi, const __bf16* __restrict__ E_lo) {
    int bid = blockIdx.x;
    int c = bid >> 6;
    int j = (bid >> 1) & 31;
    int bh = bid & 1;
    int w = threadIdx.x >> 6, lane = threadIdx.x & 63;
    int fr = lane & 15, fq = lane >> 4;
    bf16x8 Eh[2], El[2];
#pragma unroll
    for (int kk = 0; kk < 2; ++kk) {
        int off = j * 4096 + (w * 16 + fr) * 64 + fq * 8 + kk * 32;
        Eh[kk] = *(const bf16x8*)(E_hi + off);
        El[kk] = *(const bf16x8*)(E_lo + off);
    }
    int t = c * LCH + j;
#pragma unroll
    for (int mt = 0; mt < 4; ++mt) {
        int b0 = bh * 64 + mt * 16;
        bf16x8 Sh[2], Sl[2];
#pragma unroll
        for (int kk = 0; kk < 2; ++kk) {
            long off = (long)c * 8192 + (b0 + fr) * 64 + fq * 8 + kk * 32;
            Sh[kk] = *(const bf16x8*)(S_hi + off);
            Sl[kk] = *(const bf16x8*)(S_lo + off);
        }
        f32x4 acc = {0.f, 0.f, 0.f, 0.f};
#pragma unroll
        for (int kk = 0; kk < 2; ++kk) {
            acc = MFMA16(Sh[kk], Eh[kk], acc);
            acc = MFMA16(Sh[kk], El[kk], acc);
            acc = MFMA16(Sl[kk], Eh[kk], acc);
        }
#pragma unroll
        for (int r = 0; r < 4; ++r) {
            long yi = ((long)(b0 + fq * 4 + r) * T_SEQ + t) * 64 + w * 16 + fr;
            y[yi] += acc[r];
        }
    }
}

extern "C" void kernel_launch(void* const* d_in, const int* in_sizes, int n_in,
                              void* d_out, int out_size, void* d_ws, size_t ws_size,
                              hipStream_t stream) {
    const float* x = (const float*)d_in[0];
    const float* A = (const float*)d_in[1];
    const float* B = (const float*)d_in[2];
    const float* C = (const float*)d_in[3];
    const float* D = (const float*)d_in[4];
    float* y = (float*)d_out;

    char* ws = (char*)d_ws;
    float*  fstate = (float*)(ws);                      // 64*128*64*4 = 2 MB
    __bf16* S_hi   = (__bf16*)(ws + 2097152);           // 1 MB
    __bf16* S_lo   = (__bf16*)(ws + 3145728);           // 1 MB
    __bf16* E_hi   = (__bf16*)(ws + 4194304);           // 256 KB
    __bf16* E_lo   = (__bf16*)(ws + 4456448);           // 256 KB
    float*  P32    = (float*)(ws + 4718592);            // 16 KB
    __bf16* A_hi   = (__bf16*)(ws + 4734976);
    __bf16* A_lo   = (__bf16*)(ws + 4743168);
    __bf16* B_hi   = (__bf16*)(ws + 4751360);
    __bf16* B_lo   = (__bf16*)(ws + 4759552);
    __bf16* C_hi   = (__bf16*)(ws + 4767744);
    __bf16* C_lo   = (__bf16*)(ws + 4775936);
    __bf16* D_bf   = (__bf16*)(ws + 4784128);

    k_prep<<<33, 256, 0, stream>>>(A, B, C, D, P32, E_hi, E_lo,
                                   A_hi, A_lo, B_hi, B_lo, C_hi, C_lo, D_bf);
    k_pass1<<<512, 256, 0, stream>>>(x, A_hi, A_lo, B_hi, B_lo, C_hi, C_lo, D_bf,
                                     fstate, y);
    k_boundary<<<32, 256, 0, stream>>>(P32, fstate, S_hi, S_lo);
    k_corr<<<4096, 256, 0, stream>>>(y, S_hi, S_lo, E_hi, E_lo);
}

// Round 6
// 102.650 us; speedup vs baseline: 4.1060x; 1.2807x over previous
//
#include <hip/hip_runtime.h>

// SSM: h_t = A h_{t-1} + B x_t ; y_t = C h_t + D x_t
// BATCH=128, T=2048, N=64, f32. A symmetric -> keep state transposed:
//   G = h^T (64 x 16batch):  G_t = A*G_{t-1} + B*x_t^T   (A symmetric)
// One wave owns the whole recurrence for 16 batches: A,B,C,D fragments in
// VGPRs, per-step G transpose (D-layout -> B-frag) via wave-private LDS,
// NO barriers anywhere in the scan.
//
// Kernels:
//   k_prep:   bid0: A^2..A^256 by 8 split-MFMA squarings (emit A^16, A^256 f32)
//             bid1: A/B splits (hi+lo bf16), C/D bf16
//   k_scan1:  128 chunks x 16 steps, from 0 -> chunk-final states f (4MB)
//   k_bound1/k_bsuper/k_bound2: 2-level boundary scan, f becomes chunk ENTRY states (in-place)
//   k_scan2:  re-scan from entry states, write y = C h + D x directly (no RMW)

#define T_SEQ 2048
#define LCH 16       // chunk length
#define NCH 128      // chunks
#define NSUP 8       // supers of 16 chunks

typedef __bf16 bf16x8 __attribute__((ext_vector_type(8)));
typedef __bf16 bf16x4 __attribute__((ext_vector_type(4)));
typedef float f32x4 __attribute__((ext_vector_type(4)));
#define MFMA16(a, b, c) __builtin_amdgcn_mfma_f32_16x16x32_bf16(a, b, c, 0, 0, 0)

__device__ __forceinline__ float bcast(float v, int l) {
    return __int_as_float(__builtin_amdgcn_readlane(__float_as_int(v), l));
}

__device__ __forceinline__ bf16x8 cvt8(f32x4 a, f32x4 b) {
    bf16x8 o;
#pragma unroll
    for (int i = 0; i < 4; ++i) { o[i] = (__bf16)a[i]; o[4 + i] = (__bf16)b[i]; }
    return o;
}

__device__ __forceinline__ void split8(f32x4 a, f32x4 b, bf16x8& hi, bf16x8& lo) {
#pragma unroll
    for (int i = 0; i < 4; ++i) {
        float v = a[i]; __bf16 h = (__bf16)v; hi[i] = h; lo[i] = (__bf16)(v - (float)h);
        v = b[i]; h = (__bf16)v; hi[4 + i] = h; lo[4 + i] = (__bf16)(v - (float)h);
    }
}

// ---------------- k_prep ----------------
// In-LDS split matmul: D = X @ Y, Y symmetric (B-operand row-read). 4 waves.
__device__ __forceinline__ void mmstep(int w, int fr, int fq,
        const __bf16 (*Xh)[72], const __bf16 (*Xl)[72],
        const __bf16 (*Yh)[72], const __bf16 (*Yl)[72],
        __bf16 (*Dh)[72], __bf16 (*Dl)[72]) {
    f32x4 accs[4];
#pragma unroll
    for (int mt = 0; mt < 4; ++mt) {
        f32x4 acc = {0.f, 0.f, 0.f, 0.f};
#pragma unroll
        for (int kk = 0; kk < 2; ++kk) {
            bf16x8 xh = *(const bf16x8*)&Xh[mt * 16 + fr][fq * 8 + kk * 32];
            bf16x8 xl = *(const bf16x8*)&Xl[mt * 16 + fr][fq * 8 + kk * 32];
            bf16x8 yh = *(const bf16x8*)&Yh[w * 16 + fr][fq * 8 + kk * 32];
            bf16x8 yl = *(const bf16x8*)&Yl[w * 16 + fr][fq * 8 + kk * 32];
            acc = MFMA16(xh, yh, acc);
            acc = MFMA16(xh, yl, acc);
            acc = MFMA16(xl, yh, acc);
        }
        accs[mt] = acc;
    }
    __syncthreads();
#pragma unroll
    for (int mt = 0; mt < 4; ++mt)
#pragma unroll
        for (int r = 0; r < 4; ++r) {
            float v = accs[mt][r]; __bf16 h = (__bf16)v;
            Dh[mt * 16 + fq * 4 + r][w * 16 + fr] = h;
            Dl[mt * 16 + fq * 4 + r][w * 16 + fr] = (__bf16)(v - (float)h);
        }
    __syncthreads();
}

__global__ __launch_bounds__(256) void k_prep(const float* __restrict__ A,
        const float* __restrict__ B, const float* __restrict__ C,
        const float* __restrict__ D, float* __restrict__ P16f,
        float* __restrict__ P256f,
        __bf16* __restrict__ A_hi, __bf16* __restrict__ A_lo,
        __bf16* __restrict__ B_hi, __bf16* __restrict__ B_lo,
        __bf16* __restrict__ C_bf, __bf16* __restrict__ D_bf) {
    if (blockIdx.x == 1) {
        for (int i = threadIdx.x; i < 4096; i += 256) {
            float a = A[i]; __bf16 h = (__bf16)a;
            A_hi[i] = h; A_lo[i] = (__bf16)(a - (float)h);
            float b = B[i]; h = (__bf16)b;
            B_hi[i] = h; B_lo[i] = (__bf16)(b - (float)h);
            C_bf[i] = (__bf16)C[i];
            D_bf[i] = (__bf16)D[i];
        }
        return;
    }
    __shared__ __align__(16) __bf16 X1h[64][72], X1l[64][72];
    __shared__ __align__(16) __bf16 X2h[64][72], X2l[64][72];
    int w = threadIdx.x >> 6, lane = threadIdx.x & 63;
    int fr = lane & 15, fq = lane >> 4;
    for (int i = threadIdx.x; i < 4096; i += 256) {
        int r = i >> 6, cc = i & 63;
        float a = A[i]; __bf16 h = (__bf16)a;
        X1h[r][cc] = h; X1l[r][cc] = (__bf16)(a - (float)h);
    }
    __syncthreads();
    __bf16 (*curh)[72] = X1h, (*curl)[72] = X1l;
    __bf16 (*oth)[72] = X2h, (*otl)[72] = X2l;
    for (int sq = 0; sq < 8; ++sq) {
        mmstep(w, fr, fq, curh, curl, curh, curl, oth, otl);
        { __bf16 (*t1)[72] = curh; curh = oth; oth = t1;
          __bf16 (*t2)[72] = curl; curl = otl; otl = t2; }
        if (sq == 3) {
            for (int i = threadIdx.x; i < 4096; i += 256)
                P16f[i] = (float)curh[i >> 6][i & 63] + (float)curl[i >> 6][i & 63];
        }
    }
    for (int i = threadIdx.x; i < 4096; i += 256)
        P256f[i] = (float)curh[i >> 6][i & 63] + (float)curl[i >> 6][i & 63];
}

// ---------------- scan step (shared by scan1/scan2) ----------------
// Layouts (mfma_f32_16x16x32_bf16, verified by round-4 pass):
//   A-op: lane l -> M[row=l&15 (+16t)][k=(l>>4)*8+i (+32kk)]
//   B-op: lane l -> M[k=(l>>4)*8+i (+32kk)][col=l&15]
//   C/D : lane l -> D[row=(l>>4)*4+r (+16t)][col=l&15]
template<bool DOY>
__device__ __forceinline__ void sstep(
        const bf16x8 (&Afh)[4][2], const bf16x8 (&Afl)[4][2],
        const bf16x8 (&Bfh)[4][2], const bf16x8 (&Bfl)[4][2],
        const bf16x8 (&Cf)[4][2],  const bf16x8 (&Df)[4][2],
        bf16x8 (&GIH)[2], bf16x8 (&GIL)[2],
        bf16x8 (&GOH)[2], bf16x8 (&GOL)[2],
        f32x4 (&UI)[4], f32x4 (&UO)[4],
        bf16x8 (&XBC)[2], bf16x8 (&XBN)[2], f32x4 (&XRN)[4],
        f32x4 (&acc)[4],
        __bf16 (*gh)[64][8], __bf16 (*gl)[64][8],
        const float* __restrict__ xbase, float* __restrict__ ybase,
        int tj, int b, int q) {
    // convert next-step x; issue load for step j+2
    XBN[0] = cvt8(XRN[0], XRN[1]);
    XBN[1] = cvt8(XRN[2], XRN[3]);
    {
        int tl = tj + 3; if (tl > T_SEQ - 1) tl = T_SEQ - 1;
        const float* xq = xbase + tl * 64 + q * 8;
        XRN[0] = *(const f32x4*)(xq);      XRN[1] = *(const f32x4*)(xq + 4);
        XRN[2] = *(const f32x4*)(xq + 32); XRN[3] = *(const f32x4*)(xq + 36);
    }
    // chain: acc[t] = A*G_{j-1} + u_j  (3-mult split, 2 half-chains)
#pragma unroll
    for (int t = 0; t < 4; ++t) {
        f32x4 a = UI[t];
        a = MFMA16(Afl[t][0], GIH[0], a);
        a = MFMA16(Afh[t][0], GIL[0], a);
        a = MFMA16(Afh[t][0], GIH[0], a);
        f32x4 bb = {0.f, 0.f, 0.f, 0.f};
        bb = MFMA16(Afl[t][1], GIH[1], bb);
        bb = MFMA16(Afh[t][1], GIL[1], bb);
        bb = MFMA16(Afh[t][1], GIH[1], bb);
        acc[t] = a + bb;
    }
    // u_{j+1} = B * x_{j+1}^T  (off critical path)
#pragma unroll
    for (int t = 0; t < 4; ++t) {
        f32x4 un = {0.f, 0.f, 0.f, 0.f};
        un = MFMA16(Bfh[t][0], XBN[0], un);
        un = MFMA16(Bfl[t][0], XBN[0], un);
        un = MFMA16(Bfh[t][1], XBN[1], un);
        un = MFMA16(Bfl[t][1], XBN[1], un);
        UO[t] = un;
    }
    // split G_j and transpose via wave-private LDS (no barrier)
#pragma unroll
    for (int t = 0; t < 4; ++t) {
        bf16x4 h4, l4;
#pragma unroll
        for (int r = 0; r < 4; ++r) {
            __bf16 hh = (__bf16)acc[t][r];
            h4[r] = hh; l4[r] = (__bf16)(acc[t][r] - (float)hh);
        }
        int u = b * 4 + 2 * (t & 1) + (q >> 1), i0 = 4 * (q & 1);
        *(bf16x4*)&gh[t >> 1][u][i0] = h4;
        *(bf16x4*)&gl[t >> 1][u][i0] = l4;
    }
#pragma unroll
    for (int kk = 0; kk < 2; ++kk) {
        GOH[kk] = *(const bf16x8*)&gh[kk][b * 4 + q][0];
        GOL[kk] = *(const bf16x8*)&gl[kk][b * 4 + q][0];
    }
    if (DOY) {
        // y_j^T = C*G_j + D*x_j^T ; store 4 contiguous f32 per tile
#pragma unroll
        for (int t = 0; t < 4; ++t) {
            f32x4 ya = {0.f, 0.f, 0.f, 0.f};
            ya = MFMA16(Cf[t][0], GOH[0], ya);
            ya = MFMA16(Cf[t][0], GOL[0], ya);
            ya = MFMA16(Df[t][0], XBC[0], ya);
            ya = MFMA16(Cf[t][1], GOH[1], ya);
            ya = MFMA16(Cf[t][1], GOL[1], ya);
            ya = MFMA16(Df[t][1], XBC[1], ya);
            *(f32x4*)(ybase + (long)tj * 64 + 16 * t + 4 * q) = ya;
        }
    }
}

// ---------------- k_scan1: chunk-final states ----------------
__global__ __launch_bounds__(256, 1) void k_scan1(const float* __restrict__ x,
        const __bf16* __restrict__ A_hi, const __bf16* __restrict__ A_lo,
        const __bf16* __restrict__ B_hi, const __bf16* __restrict__ B_lo,
        float* __restrict__ fbuf) {
    __shared__ __bf16 GH[4][2][64][8], GL[4][2][64][8];
    int w = threadIdx.x >> 6, lane = threadIdx.x & 63;
    int b = lane & 15, q = lane >> 4;
    int wid = blockIdx.x * 4 + w;
    int g = wid >> 7, c = wid & 127;
    int t0 = c * LCH;

    bf16x8 Afh[4][2], Afl[4][2], Bfh[4][2], Bfl[4][2];
#pragma unroll
    for (int t = 0; t < 4; ++t)
#pragma unroll
        for (int kk = 0; kk < 2; ++kk) {
            int off = (16 * t + b) * 64 + q * 8 + kk * 32;
            Afh[t][kk] = *(const bf16x8*)(A_hi + off);
            Afl[t][kk] = *(const bf16x8*)(A_lo + off);
            Bfh[t][kk] = *(const bf16x8*)(B_hi + off);
            Bfl[t][kk] = *(const bf16x8*)(B_lo + off);
        }
    const float* xbase = x + (long)(g * 16 + b) * T_SEQ * 64;

    bf16x8 GAH[2], GAL[2], GBH[2], GBL[2];
#pragma unroll
    for (int kk = 0; kk < 2; ++kk) {
        GAH[kk] = (bf16x8)(__bf16)0.f; GAL[kk] = (bf16x8)(__bf16)0.f;
    }
    f32x4 xrA[4], xrB[4];
    {
        const float* xq = xbase + (long)t0 * 64 + q * 8;
        xrA[0] = *(const f32x4*)(xq);      xrA[1] = *(const f32x4*)(xq + 4);
        xrA[2] = *(const f32x4*)(xq + 32); xrA[3] = *(const f32x4*)(xq + 36);
        xq += 64;
        xrB[0] = *(const f32x4*)(xq);      xrB[1] = *(const f32x4*)(xq + 4);
        xrB[2] = *(const f32x4*)(xq + 32); xrB[3] = *(const f32x4*)(xq + 36);
    }
    bf16x8 xbA[2], xbB[2];
    xbA[0] = cvt8(xrA[0], xrA[1]); xbA[1] = cvt8(xrA[2], xrA[3]);
    f32x4 uA[4], uB[4];
#pragma unroll
    for (int t = 0; t < 4; ++t) {
        f32x4 un = {0.f, 0.f, 0.f, 0.f};
        un = MFMA16(Bfh[t][0], xbA[0], un);
        un = MFMA16(Bfl[t][0], xbA[0], un);
        un = MFMA16(Bfh[t][1], xbA[1], un);
        un = MFMA16(Bfl[t][1], xbA[1], un);
        uA[t] = un;
    }
    {
        const float* xq = xbase + (long)(t0 + 2) * 64 + q * 8;
        xrA[0] = *(const f32x4*)(xq);      xrA[1] = *(const f32x4*)(xq + 4);
        xrA[2] = *(const f32x4*)(xq + 32); xrA[3] = *(const f32x4*)(xq + 36);
    }
    f32x4 acc[4];
#pragma unroll
    for (int jj = 0; jj < 8; ++jj) {
        sstep<false>(Afh, Afl, Bfh, Bfl, Afh, Afl, GAH, GAL, GBH, GBL,
                     uA, uB, xbA, xbB, xrB, acc, &GH[w][0], &GL[w][0],
                     xbase, nullptr, t0 + 2 * jj, b, q);
        sstep<false>(Afh, Afl, Bfh, Bfl, Afh, Afl, GBH, GBL, GAH, GAL,
                     uB, uA, xbB, xbA, xrA, acc, &GH[w][0], &GL[w][0],
                     xbase, nullptr, t0 + 2 * jj + 1, b, q);
    }
    float* fp = fbuf + ((long)c * 128 + g * 16 + b) * 64;
#pragma unroll
    for (int t = 0; t < 4; ++t)
        *(f32x4*)(fp + 16 * t + 4 * q) = acc[t];
}

// ---------------- boundary scans (2-level, in-place entry states) ----------
__global__ __launch_bounds__(256) void k_bound1(const float* __restrict__ P16f,
        const float* __restrict__ fbuf, float* __restrict__ Fsup) {
    int wid = blockIdx.x * 4 + (threadIdx.x >> 6);
    int lane = threadIdx.x & 63;
    int s = wid >> 7, batch = wid & 127;
    float Pr[64];
    const f32x4* P4 = (const f32x4*)(P16f + lane * 64);
#pragma unroll
    for (int qq = 0; qq < 16; ++qq) {
        f32x4 v = P4[qq];
        Pr[qq*4] = v[0]; Pr[qq*4+1] = v[1]; Pr[qq*4+2] = v[2]; Pr[qq*4+3] = v[3];
    }
    float S = 0.f;
    for (int i = 0; i < LCH; ++i) {
        int c = s * LCH + i;
        float fv = fbuf[((long)c * 128 + batch) * 64 + lane];
        float a0 = fv, a1 = 0.f;
#pragma unroll
        for (int m = 0; m < 64; m += 2) {
            a0 = fmaf(Pr[m],     bcast(S, m),     a0);
            a1 = fmaf(Pr[m + 1], bcast(S, m + 1), a1);
        }
        S = a0 + a1;
    }
    Fsup[((long)s * 128 + batch) * 64 + lane] = S;
}

__global__ __launch_bounds__(256) void k_bsuper(const float* __restrict__ P256f,
        float* __restrict__ Fsup) {
    int batch = blockIdx.x * 4 + (threadIdx.x >> 6);
    int lane = threadIdx.x & 63;
    float Pr[64];
    const f32x4* P4 = (const f32x4*)(P256f + lane * 64);
#pragma unroll
    for (int qq = 0; qq < 16; ++qq) {
        f32x4 v = P4[qq];
        Pr[qq*4] = v[0]; Pr[qq*4+1] = v[1]; Pr[qq*4+2] = v[2]; Pr[qq*4+3] = v[3];
    }
    float E = 0.f;
    for (int s = 0; s < NSUP; ++s) {
        long idx = ((long)s * 128 + batch) * 64 + lane;
        float tmp = Fsup[idx];
        Fsup[idx] = E;
        float a0 = tmp, a1 = 0.f;
#pragma unroll
        for (int m = 0; m < 64; m += 2) {
            a0 = fmaf(Pr[m],     bcast(E, m),     a0);
            a1 = fmaf(Pr[m + 1], bcast(E, m + 1), a1);
        }
        E = a0 + a1;
    }
}

__global__ __launch_bounds__(256) void k_bound2(const float* __restrict__ P16f,
        const float* __restrict__ Fsup, float* __restrict__ fbuf) {
    int wid = blockIdx.x * 4 + (threadIdx.x >> 6);
    int lane = threadIdx.x & 63;
    int s = wid >> 7, batch = wid & 127;
    float Pr[64];
    const f32x4* P4 = (const f32x4*)(P16f + lane * 64);
#pragma unroll
    for (int qq = 0; qq < 16; ++qq) {
        f32x4 v = P4[qq];
        Pr[qq*4] = v[0]; Pr[qq*4+1] = v[1]; Pr[qq*4+2] = v[2]; Pr[qq*4+3] = v[3];
    }
    float S = Fsup[((long)s * 128 + batch) * 64 + lane];
    for (int i = 0; i < LCH; ++i) {
        int c = s * LCH + i;
        long idx = ((long)c * 128 + batch) * 64 + lane;
        float tmp = fbuf[idx];
        fbuf[idx] = S;                 // entry state of chunk c
        float a0 = tmp, a1 = 0.f;
#pragma unroll
        for (int m = 0; m < 64; m += 2) {
            a0 = fmaf(Pr[m],     bcast(S, m),     a0);
            a1 = fmaf(Pr[m + 1], bcast(S, m + 1), a1);
        }
        S = a0 + a1;
    }
}

// ---------------- k_scan2: re-scan from entry states, write y ------------
__global__ __launch_bounds__(256, 1) void k_scan2(const float* __restrict__ x,
        const float* __restrict__ Sbuf,
        const __bf16* __restrict__ A_hi, const __bf16* __restrict__ A_lo,
        const __bf16* __restrict__ B_hi, const __bf16* __restrict__ B_lo,
        const __bf16* __restrict__ C_bf, const __bf16* __restrict__ D_bf,
        float* __restrict__ y) {
    __shared__ __bf16 GH[4][2][64][8], GL[4][2][64][8];
    int w = threadIdx.x >> 6, lane = threadIdx.x & 63;
    int b = lane & 15, q = lane >> 4;
    int wid = blockIdx.x * 4 + w;
    int g = wid >> 7, c = wid & 127;
    int t0 = c * LCH;

    bf16x8 Afh[4][2], Afl[4][2], Bfh[4][2], Bfl[4][2], Cf[4][2], Df[4][2];
#pragma unroll
    for (int t = 0; t < 4; ++t)
#pragma unroll
        for (int kk = 0; kk < 2; ++kk) {
            int off = (16 * t + b) * 64 + q * 8 + kk * 32;
            Afh[t][kk] = *(const bf16x8*)(A_hi + off);
            Afl[t][kk] = *(const bf16x8*)(A_lo + off);
            Bfh[t][kk] = *(const bf16x8*)(B_hi + off);
            Bfl[t][kk] = *(const bf16x8*)(B_lo + off);
            Cf[t][kk]  = *(const bf16x8*)(C_bf + off);
            Df[t][kk]  = *(const bf16x8*)(D_bf + off);
        }
    const float* xbase = x + (long)(g * 16 + b) * T_SEQ * 64;
    float* ybase = y + (long)(g * 16 + b) * T_SEQ * 64;

    bf16x8 GAH[2], GAL[2], GBH[2], GBL[2];
    {
        const float* Sp = Sbuf + ((long)c * 128 + g * 16 + b) * 64;
        f32x4 s0 = *(const f32x4*)(Sp + q * 8);
        f32x4 s1 = *(const f32x4*)(Sp + q * 8 + 4);
        f32x4 s2 = *(const f32x4*)(Sp + 32 + q * 8);
        f32x4 s3 = *(const f32x4*)(Sp + 36 + q * 8);
        split8(s0, s1, GAH[0], GAL[0]);
        split8(s2, s3, GAH[1], GAL[1]);
    }
    f32x4 xrA[4], xrB[4];
    {
        const float* xq = xbase + (long)t0 * 64 + q * 8;
        xrA[0] = *(const f32x4*)(xq);      xrA[1] = *(const f32x4*)(xq + 4);
        xrA[2] = *(const f32x4*)(xq + 32); xrA[3] = *(const f32x4*)(xq + 36);
        xq += 64;
        xrB[0] = *(const f32x4*)(xq);      xrB[1] = *(const f32x4*)(xq + 4);
        xrB[2] = *(const f32x4*)(xq + 32); xrB[3] = *(const f32x4*)(xq + 36);
    }
    bf16x8 xbA[2], xbB[2];
    xbA[0] = cvt8(xrA[0], xrA[1]); xbA[1] = cvt8(xrA[2], xrA[3]);
    f32x4 uA[4], uB[4];
#pragma unroll
    for (int t = 0; t < 4; ++t) {
        f32x4 un = {0.f, 0.f, 0.f, 0.f};
        un = MFMA16(Bfh[t][0], xbA[0], un);
        un = MFMA16(Bfl[t][0], xbA[0], un);
        un = MFMA16(Bfh[t][1], xbA[1], un);
        un = MFMA16(Bfl[t][1], xbA[1], un);
        uA[t] = un;
    }
    {
        const float* xq = xbase + (long)(t0 + 2) * 64 + q * 8;
        xrA[0] = *(const f32x4*)(xq);      xrA[1] = *(const f32x4*)(xq + 4);
        xrA[2] = *(const f32x4*)(xq + 32); xrA[3] = *(const f32x4*)(xq + 36);
    }
    f32x4 acc[4];
#pragma unroll
    for (int jj = 0; jj < 8; ++jj) {
        sstep<true>(Afh, Afl, Bfh, Bfl, Cf, Df, GAH, GAL, GBH, GBL,
                    uA, uB, xbA, xbB, xrB, acc, &GH[w][0], &GL[w][0],
                    xbase, ybase, t0 + 2 * jj, b, q);
        sstep<true>(Afh, Afl, Bfh, Bfl, Cf, Df, GBH, GBL, GAH, GAL,
                    uB, uA, xbB, xbA, xrA, acc, &GH[w][0], &GL[w][0],
                    xbase, ybase, t0 + 2 * jj + 1, b, q);
    }
}

extern "C" void kernel_launch(void* const* d_in, const int* in_sizes, int n_in,
                              void* d_out, int out_size, void* d_ws, size_t ws_size,
                              hipStream_t stream) {
    const float* x = (const float*)d_in[0];
    const float* A = (const float*)d_in[1];
    const float* B = (const float*)d_in[2];
    const float* C = (const float*)d_in[3];
    const float* D = (const float*)d_in[4];
    float* y = (float*)d_out;

    char* ws = (char*)d_ws;
    float*  fbuf  = (float*)(ws);                 // 128*128*64*4 = 4 MB
    float*  Fsup  = (float*)(ws + 4194304);       // 8*128*64*4 = 256 KB
    float*  P16f  = (float*)(ws + 4456448);       // 16 KB
    float*  P256f = (float*)(ws + 4472832);       // 16 KB
    __bf16* A_hi  = (__bf16*)(ws + 4489216);      // 8 KB each
    __bf16* A_lo  = (__bf16*)(ws + 4497408);
    __bf16* B_hi  = (__bf16*)(ws + 4505600);
    __bf16* B_lo  = (__bf16*)(ws + 4513792);
    __bf16* C_bf  = (__bf16*)(ws + 4521984);
    __bf16* D_bf  = (__bf16*)(ws + 4530176);

    k_prep<<<2, 256, 0, stream>>>(A, B, C, D, P16f, P256f,
                                  A_hi, A_lo, B_hi, B_lo, C_bf, D_bf);
    k_scan1<<<256, 256, 0, stream>>>(x, A_hi, A_lo, B_hi, B_lo, fbuf);
    k_bound1<<<256, 256, 0, stream>>>(P16f, fbuf, Fsup);
    k_bsuper<<<32, 256, 0, stream>>>(P256f, Fsup);
    k_bound2<<<256, 256, 0, stream>>>(P16f, Fsup, fbuf);
    k_scan2<<<256, 256, 0, stream>>>(x, fbuf, A_hi, A_lo, B_hi, B_lo,
                                     C_bf, D_bf, y);
}

// Round 9
// 91.949 us; speedup vs baseline: 4.5838x; 1.1164x over previous
//
#include <hip/hip_runtime.h>

// SSM: h_t = A h_{t-1} + B x_t ; y_t = C h_t + D x_t
// BATCH=128, T=2048, N=64, f32. A symmetric -> transposed state:
//   G = h^T (64 x 32batch): G_t = A*G_{t-1} + B*x_t^T
// 32x32x16 MFMA tiles, 32 batches/wave, NO LDS in scans; state feedback
// (C/D layout -> B-operand frags) via permlane32_swap (16 swaps/step).
// A split hi/lo (3-mult); B,C,D,x plain bf16.
// Round 9: plswap switched from RAW INLINE ASM to
// __builtin_amdgcn_permlane32_swap -- raw asm bypasses the compiler's
// VALU<->permlane hazard s_nop insertion on gfx950, reading undefined
// VGPR data (NaN bf16 patterns) -> round-7/8 NaN. Everything else
// identical to round 8 (ws footprint 4.53 MB, proven in round 6).

#define T_SEQ 2048
#define LCH 16
#define NCH 128
#define NSUP 8

typedef __bf16 bf16x8 __attribute__((ext_vector_type(8)));
typedef float f32x4 __attribute__((ext_vector_type(4)));
typedef float f32x16 __attribute__((ext_vector_type(16)));
typedef unsigned int u32;
typedef unsigned int u32x2 __attribute__((ext_vector_type(2)));

#define MFMA32(a, b, c) __builtin_amdgcn_mfma_f32_32x32x16_bf16(a, b, c, 0, 0, 0)
#define MFMA16(a, b, c) __builtin_amdgcn_mfma_f32_16x16x32_bf16(a, b, c, 0, 0, 0)

__device__ __forceinline__ float bcast(float v, int l) {
    return __int_as_float(__builtin_amdgcn_readlane(__float_as_int(v), l));
}
__device__ __forceinline__ u32 pk2f(float a, float b) {
    union { __bf16 h[2]; u32 u; } z;
    z.h[0] = (__bf16)a; z.h[1] = (__bf16)b; return z.u;
}
__device__ __forceinline__ u32 pk2h(__bf16 a, __bf16 b) {
    union { __bf16 h[2]; u32 u; } z;
    z.h[0] = a; z.h[1] = b; return z.u;
}
__device__ __forceinline__ bf16x8 mk8(u32 a, u32 b, u32 c, u32 d) {
    union { u32 u[4]; bf16x8 v; } z;
    z.u[0] = a; z.u[1] = b; z.u[2] = c; z.u[3] = d; return z.v;
}
// swap upper 32 lanes of a with lower 32 lanes of b (both updated).
// Builtin (NOT raw asm): compiler handles gfx950 VALU<->permlane hazards.
__device__ __forceinline__ void plswap(u32& a, u32& b) {
    u32x2 r = __builtin_amdgcn_permlane32_swap(a, b, false, false);
    a = r[0]; b = r[1];
}
__device__ __forceinline__ f32x16 z16() {
    f32x16 z;
#pragma unroll
    for (int e = 0; e < 16; ++e) z[e] = 0.f;
    return z;
}
__device__ __forceinline__ void split8(f32x4 a, f32x4 b, bf16x8& hi, bf16x8& lo) {
#pragma unroll
    for (int i = 0; i < 4; ++i) {
        float v = a[i]; __bf16 h = (__bf16)v; hi[i] = h; lo[i] = (__bf16)(v - (float)h);
        v = b[i]; h = (__bf16)v; hi[4 + i] = h; lo[4 + i] = (__bf16)(v - (float)h);
    }
}

// C/D tile (f32x16) -> B-operand frags (kc=0,1) hi+lo, via permlane swaps.
// C/D: reg r -> row (r&3)+8*(r>>2)+4*hl.  B-frag kc: elem e -> row 16kc+8hl+e.
__device__ __forceinline__ void feedback(const f32x16& ac,
        bf16x8& gh0, bf16x8& gl0, bf16x8& gh1, bf16x8& gl1) {
    __bf16 hb[16]; float lo[16];
#pragma unroll
    for (int e = 0; e < 16; ++e) { hb[e] = (__bf16)ac[e]; lo[e] = ac[e] - (float)hb[e]; }
    u32 a0 = pk2h(hb[0], hb[1]),  a1 = pk2h(hb[2], hb[3]);
    u32 b0 = pk2h(hb[4], hb[5]),  b1 = pk2h(hb[6], hb[7]);
    u32 c0 = pk2h(hb[8], hb[9]),  c1 = pk2h(hb[10], hb[11]);
    u32 d0 = pk2h(hb[12], hb[13]), d1 = pk2h(hb[14], hb[15]);
    plswap(a0, b0); plswap(a1, b1);
    gh0 = mk8(a0, a1, b0, b1);
    plswap(c0, d0); plswap(c1, d1);
    gh1 = mk8(c0, c1, d0, d1);
    u32 e0 = pk2f(lo[0], lo[1]),  e1 = pk2f(lo[2], lo[3]);
    u32 f0 = pk2f(lo[4], lo[5]),  f1 = pk2f(lo[6], lo[7]);
    u32 g0 = pk2f(lo[8], lo[9]),  g1 = pk2f(lo[10], lo[11]);
    u32 h0 = pk2f(lo[12], lo[13]), h1 = pk2f(lo[14], lo[15]);
    plswap(e0, f0); plswap(e1, f1);
    gl0 = mk8(e0, e1, f0, f1);
    plswap(g0, h0); plswap(g1, h1);
    gl1 = mk8(g0, g1, h0, h1);
}

// ---------------- k_prep (16x16 split-MFMA squarings; round-6 proven) ------
__device__ __forceinline__ void mmstep(int w, int fr, int fq,
        const __bf16 (*Xh)[72], const __bf16 (*Xl)[72],
        const __bf16 (*Yh)[72], const __bf16 (*Yl)[72],
        __bf16 (*Dh)[72], __bf16 (*Dl)[72]) {
    f32x4 accs[4];
#pragma unroll
    for (int mt = 0; mt < 4; ++mt) {
        f32x4 acc = {0.f, 0.f, 0.f, 0.f};
#pragma unroll
        for (int kk = 0; kk < 2; ++kk) {
            bf16x8 xh = *(const bf16x8*)&Xh[mt * 16 + fr][fq * 8 + kk * 32];
            bf16x8 xl = *(const bf16x8*)&Xl[mt * 16 + fr][fq * 8 + kk * 32];
            bf16x8 yh = *(const bf16x8*)&Yh[w * 16 + fr][fq * 8 + kk * 32];
            bf16x8 yl = *(const bf16x8*)&Yl[w * 16 + fr][fq * 8 + kk * 32];
            acc = MFMA16(xh, yh, acc);
            acc = MFMA16(xh, yl, acc);
            acc = MFMA16(xl, yh, acc);
        }
        accs[mt] = acc;
    }
    __syncthreads();
#pragma unroll
    for (int mt = 0; mt < 4; ++mt)
#pragma unroll
        for (int r = 0; r < 4; ++r) {
            float v = accs[mt][r]; __bf16 h = (__bf16)v;
            Dh[mt * 16 + fq * 4 + r][w * 16 + fr] = h;
            Dl[mt * 16 + fq * 4 + r][w * 16 + fr] = (__bf16)(v - (float)h);
        }
    __syncthreads();
}

__global__ __launch_bounds__(256) void k_prep(const float* __restrict__ A,
        const float* __restrict__ B, const float* __restrict__ C,
        const float* __restrict__ D, float* __restrict__ P16f,
        float* __restrict__ P256f,
        __bf16* __restrict__ A_hi, __bf16* __restrict__ A_lo,
        __bf16* __restrict__ B_bf, __bf16* __restrict__ C_bf,
        __bf16* __restrict__ D_bf) {
    if (blockIdx.x == 1) {
        for (int i = threadIdx.x; i < 4096; i += 256) {
            float a = A[i]; __bf16 h = (__bf16)a;
            A_hi[i] = h; A_lo[i] = (__bf16)(a - (float)h);
            B_bf[i] = (__bf16)B[i];
            C_bf[i] = (__bf16)C[i];
            D_bf[i] = (__bf16)D[i];
        }
        return;
    }
    __shared__ __align__(16) __bf16 X1h[64][72], X1l[64][72];
    __shared__ __align__(16) __bf16 X2h[64][72], X2l[64][72];
    int w = threadIdx.x >> 6, lane = threadIdx.x & 63;
    int fr = lane & 15, fq = lane >> 4;
    for (int i = threadIdx.x; i < 4096; i += 256) {
        int r = i >> 6, cc = i & 63;
        float a = A[i]; __bf16 h = (__bf16)a;
        X1h[r][cc] = h; X1l[r][cc] = (__bf16)(a - (float)h);
    }
    __syncthreads();
    __bf16 (*curh)[72] = X1h, (*curl)[72] = X1l;
    __bf16 (*oth)[72] = X2h, (*otl)[72] = X2l;
    for (int sq = 0; sq < 8; ++sq) {   // A^2 .. A^256
        mmstep(w, fr, fq, curh, curl, curh, curl, oth, otl);
        { __bf16 (*t1)[72] = curh; curh = oth; oth = t1;
          __bf16 (*t2)[72] = curl; curl = otl; otl = t2; }
        if (sq == 3) {                 // A^16
            for (int i = threadIdx.x; i < 4096; i += 256)
                P16f[i] = (float)curh[i >> 6][i & 63] + (float)curl[i >> 6][i & 63];
        }
    }
    for (int i = threadIdx.x; i < 4096; i += 256)
        P256f[i] = (float)curh[i >> 6][i & 63] + (float)curl[i >> 6][i & 63];
}

// ---------------- scan core (32x32 tiles, LDS-free) ------------------------
// Layouts (mfma_f32_32x32x16_bf16):
//   A-op: lane l -> M[row=l&31][k=8*(l>>5)+e (+16kc)]
//   B-op: lane l -> M[k=8*(l>>5)+e (+16kc)][col=l&31]
//   C/D : lane l -> D[row=(r&3)+8*(r>>2)+4*(l>>5)][col=l&31]
template<bool DOY>
__device__ __forceinline__ void scan_core(const float* __restrict__ x,
        const float* __restrict__ Sbuf,
        const __bf16* __restrict__ A_hi, const __bf16* __restrict__ A_lo,
        const __bf16* __restrict__ B_bf, const __bf16* __restrict__ C_bf,
        const __bf16* __restrict__ D_bf,
        float* __restrict__ fbuf, float* __restrict__ y) {
    int lane = threadIdx.x & 63;
    int bcol = lane & 31;
    int hl = lane >> 5;
    int wid = blockIdx.x;
    int g = wid >> 7;            // batch group 0..3
    int c = wid & 127;           // chunk
    int t0 = c * LCH;
    long brow = (long)(g * 32 + bcol);

    bf16x8 Afh[2][2][2], Afl[2][2][2], Bf[2][2][2], Cf[2][2][2], Df[2][2][2];
#pragma unroll
    for (int i = 0; i < 2; ++i)
#pragma unroll
        for (int j = 0; j < 2; ++j)
#pragma unroll
            for (int kc = 0; kc < 2; ++kc) {
                int off = (32 * i + bcol) * 64 + 32 * j + 16 * kc + 8 * hl;
                Afh[i][j][kc] = *(const bf16x8*)(A_hi + off);
                Afl[i][j][kc] = *(const bf16x8*)(A_lo + off);
                Bf[i][j][kc]  = *(const bf16x8*)(B_bf + off);
                if (DOY) {
                    Cf[i][j][kc] = *(const bf16x8*)(C_bf + off);
                    Df[i][j][kc] = *(const bf16x8*)(D_bf + off);
                }
            }

    bf16x8 Gh[2][2], Gl[2][2];
    if (DOY) {
        const float* Sp = Sbuf + ((long)c * 128 + brow) * 64;
#pragma unroll
        for (int jr = 0; jr < 2; ++jr)
#pragma unroll
            for (int kc = 0; kc < 2; ++kc) {
                int n0 = 32 * jr + 16 * kc + 8 * hl;
                f32x4 s0 = *(const f32x4*)(Sp + n0);
                f32x4 s1 = *(const f32x4*)(Sp + n0 + 4);
                split8(s0, s1, Gh[jr][kc], Gl[jr][kc]);
            }
    } else {
#pragma unroll
        for (int jr = 0; jr < 2; ++jr)
#pragma unroll
            for (int kc = 0; kc < 2; ++kc) {
                Gh[jr][kc] = (bf16x8)(__bf16)0.f;
                Gl[jr][kc] = (bf16x8)(__bf16)0.f;
            }
    }

    const float* xb = x + (brow * T_SEQ + t0) * 64 + 8 * hl;
    f32x4 XF[8]; bf16x8 XB[2][2];
#define LOADX(dt) { const float* p = xb + (long)(dt) * 64;                     \
    XF[0] = *(const f32x4*)(p);      XF[1] = *(const f32x4*)(p + 4);           \
    XF[2] = *(const f32x4*)(p + 16); XF[3] = *(const f32x4*)(p + 20);          \
    XF[4] = *(const f32x4*)(p + 32); XF[5] = *(const f32x4*)(p + 36);          \
    XF[6] = *(const f32x4*)(p + 48); XF[7] = *(const f32x4*)(p + 52); }
#define CVTX() {                                                               \
    XB[0][0] = mk8(pk2f(XF[0][0], XF[0][1]), pk2f(XF[0][2], XF[0][3]),         \
                   pk2f(XF[1][0], XF[1][1]), pk2f(XF[1][2], XF[1][3]));        \
    XB[0][1] = mk8(pk2f(XF[2][0], XF[2][1]), pk2f(XF[2][2], XF[2][3]),         \
                   pk2f(XF[3][0], XF[3][1]), pk2f(XF[3][2], XF[3][3]));        \
    XB[1][0] = mk8(pk2f(XF[4][0], XF[4][1]), pk2f(XF[4][2], XF[4][3]),         \
                   pk2f(XF[5][0], XF[5][1]), pk2f(XF[5][2], XF[5][3]));        \
    XB[1][1] = mk8(pk2f(XF[6][0], XF[6][1]), pk2f(XF[6][2], XF[6][3]),         \
                   pk2f(XF[7][0], XF[7][1]), pk2f(XF[7][2], XF[7][3])); }

    LOADX(0); CVTX(); LOADX(1);

    float* yb = DOY ? (y + brow * T_SEQ * 64) : nullptr;
    f32x16 ac0, ac1;
#pragma unroll
    for (int st = 0; st < LCH; ++st) {
        // u = B * x^T into fresh accumulators
        ac0 = z16(); ac1 = z16();
#pragma unroll
        for (int j = 0; j < 2; ++j)
#pragma unroll
            for (int kc = 0; kc < 2; ++kc) {
                ac0 = MFMA32(Bf[0][j][kc], XB[j][kc], ac0);
                ac1 = MFMA32(Bf[1][j][kc], XB[j][kc], ac1);
            }
        // + A * G  (3-mult split)
#pragma unroll
        for (int jr = 0; jr < 2; ++jr)
#pragma unroll
            for (int kc = 0; kc < 2; ++kc) {
                ac0 = MFMA32(Afh[0][jr][kc], Gh[jr][kc], ac0);
                ac0 = MFMA32(Afh[0][jr][kc], Gl[jr][kc], ac0);
                ac0 = MFMA32(Afl[0][jr][kc], Gh[jr][kc], ac0);
                ac1 = MFMA32(Afh[1][jr][kc], Gh[jr][kc], ac1);
                ac1 = MFMA32(Afh[1][jr][kc], Gl[jr][kc], ac1);
                ac1 = MFMA32(Afl[1][jr][kc], Gh[jr][kc], ac1);
            }
        // feedback: new G frags via permlane swaps (no LDS)
        feedback(ac0, Gh[0][0], Gl[0][0], Gh[0][1], Gl[0][1]);
        feedback(ac1, Gh[1][0], Gl[1][0], Gh[1][1], Gl[1][1]);
        if (DOY) {
            float* yp = yb + (long)(t0 + st) * 64;
#pragma unroll
            for (int i = 0; i < 2; ++i) {
                f32x16 ya = z16();
#pragma unroll
                for (int jr = 0; jr < 2; ++jr)
#pragma unroll
                    for (int kc = 0; kc < 2; ++kc) {
                        ya = MFMA32(Cf[i][jr][kc], Gh[jr][kc], ya);
                        ya = MFMA32(Cf[i][jr][kc], Gl[jr][kc], ya);
                        ya = MFMA32(Df[i][jr][kc], XB[jr][kc], ya);
                    }
#pragma unroll
                for (int m = 0; m < 4; ++m) {
                    f32x4 v;
                    v[0] = ya[4 * m]; v[1] = ya[4 * m + 1];
                    v[2] = ya[4 * m + 2]; v[3] = ya[4 * m + 3];
                    *(f32x4*)(yp + 32 * i + 8 * m + 4 * hl) = v;
                }
            }
        }
        if (!DOY && st == LCH - 1) {
            float* fp = fbuf + ((long)c * 128 + brow) * 64;
#pragma unroll
            for (int m = 0; m < 4; ++m) {
                f32x4 v0, v1;
                v0[0] = ac0[4 * m]; v0[1] = ac0[4 * m + 1];
                v0[2] = ac0[4 * m + 2]; v0[3] = ac0[4 * m + 3];
                v1[0] = ac1[4 * m]; v1[1] = ac1[4 * m + 1];
                v1[2] = ac1[4 * m + 2]; v1[3] = ac1[4 * m + 3];
                *(f32x4*)(fp + 8 * m + 4 * hl) = v0;
                *(f32x4*)(fp + 32 + 8 * m + 4 * hl) = v1;
            }
        }
        // rotate x: XB <- XF(t+1); prefetch XF(t+2) (clamped)
        CVTX();
        int nt = st + 2;
        if (t0 + nt > T_SEQ - 1) nt = T_SEQ - 1 - t0;
        LOADX(nt);
    }
#undef LOADX
#undef CVTX
}

__global__ __launch_bounds__(64, 1) void k_scan1(const float* __restrict__ x,
        const __bf16* __restrict__ A_hi, const __bf16* __restrict__ A_lo,
        const __bf16* __restrict__ B_bf, float* __restrict__ fbuf) {
    scan_core<false>(x, nullptr, A_hi, A_lo, B_bf, nullptr, nullptr, fbuf, nullptr);
}

__global__ __launch_bounds__(64, 1) void k_scan2(const float* __restrict__ x,
        const float* __restrict__ Sbuf,
        const __bf16* __restrict__ A_hi, const __bf16* __restrict__ A_lo,
        const __bf16* __restrict__ B_bf, const __bf16* __restrict__ C_bf,
        const __bf16* __restrict__ D_bf, float* __restrict__ y) {
    scan_core<true>(x, Sbuf, A_hi, A_lo, B_bf, C_bf, D_bf, nullptr, y);
}

// ---------------- boundary scans (2-level, f32 readlane) -------------------
__global__ __launch_bounds__(256) void k_bound1(const float* __restrict__ P16f,
        const float* __restrict__ fbuf, float* __restrict__ Fsup) {
    int wid = blockIdx.x * 4 + (threadIdx.x >> 6);
    int lane = threadIdx.x & 63;
    int s = wid >> 7, batch = wid & 127;
    float Pr[64];
    const f32x4* P4 = (const f32x4*)(P16f + lane * 64);
#pragma unroll
    for (int qq = 0; qq < 16; ++qq) {
        f32x4 v = P4[qq];
        Pr[qq*4] = v[0]; Pr[qq*4+1] = v[1]; Pr[qq*4+2] = v[2]; Pr[qq*4+3] = v[3];
    }
    float S = 0.f;
    for (int i = 0; i < 16; ++i) {
        int c = s * 16 + i;
        float fv = fbuf[((long)c * 128 + batch) * 64 + lane];
        float a0 = fv, a1 = 0.f;
#pragma unroll
        for (int m = 0; m < 64; m += 2) {
            a0 = fmaf(Pr[m],     bcast(S, m),     a0);
            a1 = fmaf(Pr[m + 1], bcast(S, m + 1), a1);
        }
        S = a0 + a1;
    }
    Fsup[((long)s * 128 + batch) * 64 + lane] = S;
}

__global__ __launch_bounds__(256) void k_bsuper(const float* __restrict__ P256f,
        float* __restrict__ Fsup) {
    int batch = blockIdx.x * 4 + (threadIdx.x >> 6);
    int lane = threadIdx.x & 63;
    float Pr[64];
    const f32x4* P4 = (const f32x4*)(P256f + lane * 64);
#pragma unroll
    for (int qq = 0; qq < 16; ++qq) {
        f32x4 v = P4[qq];
        Pr[qq*4] = v[0]; Pr[qq*4+1] = v[1]; Pr[qq*4+2] = v[2]; Pr[qq*4+3] = v[3];
    }
    float E = 0.f;
    for (int s = 0; s < NSUP; ++s) {
        long idx = ((long)s * 128 + batch) * 64 + lane;
        float tmp = Fsup[idx];
        Fsup[idx] = E;
        float a0 = tmp, a1 = 0.f;
#pragma unroll
        for (int m = 0; m < 64; m += 2) {
            a0 = fmaf(Pr[m],     bcast(E, m),     a0);
            a1 = fmaf(Pr[m + 1], bcast(E, m + 1), a1);
        }
        E = a0 + a1;
    }
}

__global__ __launch_bounds__(256) void k_bound2(const float* __restrict__ P16f,
        const float* __restrict__ Fsup, float* __restrict__ fbuf) {
    int wid = blockIdx.x * 4 + (threadIdx.x >> 6);
    int lane = threadIdx.x & 63;
    int s = wid >> 7, batch = wid & 127;
    float Pr[64];
    const f32x4* P4 = (const f32x4*)(P16f + lane * 64);
#pragma unroll
    for (int qq = 0; qq < 16; ++qq) {
        f32x4 v = P4[qq];
        Pr[qq*4] = v[0]; Pr[qq*4+1] = v[1]; Pr[qq*4+2] = v[2]; Pr[qq*4+3] = v[3];
    }
    float S = Fsup[((long)s * 128 + batch) * 64 + lane];
    for (int i = 0; i < 16; ++i) {
        int c = s * 16 + i;
        long idx = ((long)c * 128 + batch) * 64 + lane;
        float tmp = fbuf[idx];
        fbuf[idx] = S;                 // entry state of chunk c
        float a0 = tmp, a1 = 0.f;
#pragma unroll
        for (int m = 0; m < 64; m += 2) {
            a0 = fmaf(Pr[m],     bcast(S, m),     a0);
            a1 = fmaf(Pr[m + 1], bcast(S, m + 1), a1);
        }
        S = a0 + a1;
    }
}

extern "C" void kernel_launch(void* const* d_in, const int* in_sizes, int n_in,
                              void* d_out, int out_size, void* d_ws, size_t ws_size,
                              hipStream_t stream) {
    const float* x = (const float*)d_in[0];
    const float* A = (const float*)d_in[1];
    const float* B = (const float*)d_in[2];
    const float* C = (const float*)d_in[3];
    const float* D = (const float*)d_in[4];
    float* y = (float*)d_out;

    char* ws = (char*)d_ws;
    float*  fbuf = (float*)(ws);                  // 128*128*64*4 = 4 MB
    float*  Fsup = (float*)(ws + 4194304);        // 8*128*64*4 = 256 KB
    float*  P16f = (float*)(ws + 4456448);        // 16 KB
    float*  P256f= (float*)(ws + 4472832);        // 16 KB
    __bf16* A_hi = (__bf16*)(ws + 4489216);       // 8 KB each
    __bf16* A_lo = (__bf16*)(ws + 4497408);
    __bf16* B_bf = (__bf16*)(ws + 4505600);
    __bf16* C_bf = (__bf16*)(ws + 4513792);
    __bf16* D_bf = (__bf16*)(ws + 4521984);
    // total: 4,530,176 bytes (round-6-proven footprint)

    k_prep<<<2, 256, 0, stream>>>(A, B, C, D, P16f, P256f,
                                  A_hi, A_lo, B_bf, C_bf, D_bf);
    k_scan1<<<512, 64, 0, stream>>>(x, A_hi, A_lo, B_bf, fbuf);
    k_bound1<<<256, 256, 0, stream>>>(P16f, fbuf, Fsup);
    k_bsuper<<<32, 256, 0, stream>>>(P256f, Fsup);
    k_bound2<<<256, 256, 0, stream>>>(P16f, Fsup, fbuf);
    k_scan2<<<512, 64, 0, stream>>>(x, fbuf, A_hi, A_lo, B_bf, C_bf, D_bf, y);
}